// Round 16
// baseline (113.805 us; speedup 1.0000x reference)
//
#include <hip/hip_runtime.h>
#include <hip/hip_fp16.h>

#define SQRT3 1.7320508075688772f
#define INV_SQRT3 0.5773502691896258f
#define CAP 64

#define WAVE_SYNC() do { asm volatile("s_waitcnt lgkmcnt(0)" ::: "memory"); \
                         __builtin_amdgcn_wave_barrier(); } while (0)

// ---------------- fused prep: featH(f16) + zero block + pos4 + h2 weights + cnt=0 ----
// featH[node*32+cl] = half4{s_cl, v_cl0, v_cl1, v_cl2}  (256 B per node, contiguous)
// featH[N*32+cl] = 0  (zero block: padded edge slots gather exact zeros)
// WS2[u2*32+j] = h2{fs(2u2,j), fs(2u2+1,j)};  WV2 likewise (all scales folded)
__global__ void prep_kernel(const float* __restrict__ feat, const float* __restrict__ pos,
                            const float* __restrict__ Ws, const float* __restrict__ Wv,
                            const float* __restrict__ tpw,
                            uint2* __restrict__ featH, float4* __restrict__ pos4,
                            int* __restrict__ cnt,
                            __half2* __restrict__ WS2, __half2* __restrict__ WV2, int N) {
    int i = blockIdx.x * blockDim.x + threadIdx.x;
    int totalF = N * 32;
    if (i < totalF) {
        int node = i >> 5, cl = i & 31;
        const float* fb = feat + (size_t)node * 128;
        float s  = fb[cl];
        float v0 = fb[32 + 3 * cl], v1 = fb[33 + 3 * cl], v2 = fb[34 + 3 * cl];
        __half2 h0 = __floats2half2_rn(s, v0);
        __half2 h1 = __floats2half2_rn(v1, v2);
        uint2 r;
        r.x = *(const unsigned int*)&h0;
        r.y = *(const unsigned int*)&h1;
        featH[i] = r;
        return;
    }
    int j = i - totalF;
    if (j < 32) { featH[totalF + j] = make_uint2(0u, 0u); return; }   // zero block
    j -= 32;
    if (j < N) {
        pos4[j] = make_float4(pos[3 * j], pos[3 * j + 1], pos[3 * j + 2], 0.f);
        cnt[j] = 0;                        // zero scatter cursors (no memset pass)
        return;
    }
    int k = j - N;
    if (k < 1024) {                        // u2 = k>>5 in [0,32), col = k&31
        int u2 = k >> 5, c = k & 31;
        int ua = 2 * u2, ub = 2 * u2 + 1;
        auto fs = [&](int u) {
            float w = Ws[u * 32 + c];
            return (u < 32) ? 0.125f * tpw[u] * w
                            : 0.125f * tpw[96 + (u - 32)] * INV_SQRT3 * w;
        };
        auto fv = [&](int u) {
            float w = Wv[u * 32 + c];
            return (u < 32) ? 0.125f * tpw[32 + u] * w
                            : 0.125f * tpw[64 + (u - 32)] * w;
        };
        WS2[k] = __floats2half2_rn(fs(ua), fs(ub));
        WV2[k] = __floats2half2_rn(fv(ua), fv(ub));
    }
}

// ---------------- single-pass padded-CSR scatter (proven R7, byte-identical) --------
__global__ void scatter_kernel(const int* __restrict__ esrc, const int* __restrict__ edst,
                               int* __restrict__ cnt, int* __restrict__ csrP, int E) {
    int t = blockIdx.x * blockDim.x + threadIdx.x;
    int e0 = t * 4;
    if (e0 + 4 <= E) {
        int4 s4 = *(const int4*)(esrc + e0);
        int4 d4 = *(const int4*)(edst + e0);
        int p;
        p = atomicAdd(&cnt[d4.x], 1); if (p < CAP) csrP[(size_t)d4.x * CAP + p] = s4.x;
        p = atomicAdd(&cnt[d4.y], 1); if (p < CAP) csrP[(size_t)d4.y * CAP + p] = s4.y;
        p = atomicAdd(&cnt[d4.z], 1); if (p < CAP) csrP[(size_t)d4.z * CAP + p] = s4.z;
        p = atomicAdd(&cnt[d4.w], 1); if (p < CAP) csrP[(size_t)d4.w * CAP + p] = s4.w;
    } else {
        for (int e = e0; e < E; ++e) {
            int d = edst[e];
            int p = atomicAdd(&cnt[d], 1);
            if (p < CAP) csrP[(size_t)d * CAP + p] = esrc[e];
        }
    }
}

// ---------------- per-node gather + TP + linear (DUAL-node wave) ----------------
// 1 wave per TWO nodes, HALF-wave per edge, lane owns channel cl (f16x4, 8B load).
// Both nodes' edge lists padded (zero-block) to one common multiple of 8 ->
// branchless interleaved loop: 2 independent gathers per body pair, unroll 4
// -> up to 8 gathers in flight per wave (2x the single-node R7/R15 structure).

__global__ __launch_bounds__(256) void node_kernel(
    const uint2* __restrict__ featH, const float4* __restrict__ pos4,
    const int* __restrict__ csrP, const int* __restrict__ cnt,
    const __half2* __restrict__ WS2, const __half2* __restrict__ WV2,
    float* __restrict__ out, int N)
{
    __shared__ float4 geom[4][2][64];
    __shared__ float  sS[4][2][68], sX[4][2][68], sY[4][2][68], sZ[4][2][68];
    int lane = threadIdx.x & 63;
    int w    = threadIdx.x >> 6;
    int n0   = blockIdx.x * 8 + 2 * w;
    if (n0 >= N) return;                   // whole-wave exit; no block barriers used
    int n1   = n0 + 1;
    bool has1 = n1 < N;

    int len0 = cnt[n0]; len0 = len0 < CAP ? len0 : CAP;
    int len1 = 0;
    if (has1) { len1 = cnt[n1]; len1 = len1 < CAP ? len1 : CAP; }
    int lmax = len0 > len1 ? len0 : len1;
    int lenP = (lmax + 7) & ~7;            // common padded length (multiple of 8)
    int half = lane >> 5;
    int cl   = lane & 31;

    // geometry phase, node 0 then node 1 (zero-entry beyond each len)
    {
        float4 pd = pos4[n0];
        if (lane < len0) {
            int s = csrP[(size_t)n0 * CAP + lane];
            float4 ps = pos4[s];
            float ex = pd.x - ps.x, ey = pd.y - ps.y, ez = pd.z - ps.z;
            float rr = SQRT3 * rsqrtf(ex * ex + ey * ey + ez * ez + 1e-12f);
            geom[w][0][lane] = make_float4(rr * ex, rr * ey, rr * ez, __int_as_float(s));
        } else {
            geom[w][0][lane] = make_float4(0.f, 0.f, 0.f, __int_as_float(N));
        }
    }
    if (has1) {
        float4 pd = pos4[n1];
        if (lane < len1) {
            int s = csrP[(size_t)n1 * CAP + lane];
            float4 ps = pos4[s];
            float ex = pd.x - ps.x, ey = pd.y - ps.y, ez = pd.z - ps.z;
            float rr = SQRT3 * rsqrtf(ex * ex + ey * ey + ez * ez + 1e-12f);
            geom[w][1][lane] = make_float4(rr * ex, rr * ey, rr * ez, __int_as_float(s));
        } else {
            geom[w][1][lane] = make_float4(0.f, 0.f, 0.f, __int_as_float(N));
        }
    } else {
        geom[w][1][lane] = make_float4(0.f, 0.f, 0.f, __int_as_float(N));
    }
    WAVE_SYNC();

    float A0a = 0.f, A1xa = 0.f, A1ya = 0.f, A1za = 0.f;   // node0 s-channel
    float V0a = 0.f, V1a = 0.f, V2a = 0.f, T3a = 0.f;      // node0 v-channel
    float A0b = 0.f, A1xb = 0.f, A1yb = 0.f, A1zb = 0.f;   // node1 s-channel
    float V0b = 0.f, V1b = 0.f, V2b = 0.f, T3b = 0.f;      // node1 v-channel

    #pragma unroll 4
    for (int m = 0; m + 2 <= lenP; m += 2) {
        int e = m + half;
        float4 g0 = geom[w][0][e];
        float4 g1 = geom[w][1][e];
        int s0 = __float_as_int(g0.w);
        int s1 = __float_as_int(g1.w);
        uint2 f0 = featH[(size_t)s0 * 32 + cl];
        uint2 f1 = featH[(size_t)s1 * 32 + cl];
        float2 lo0 = __half22float2(*(const __half2*)&f0.x);
        float2 hi0 = __half22float2(*(const __half2*)&f0.y);
        float2 lo1 = __half22float2(*(const __half2*)&f1.x);
        float2 hi1 = __half22float2(*(const __half2*)&f1.y);
        A0a += lo0.x;
        A1xa = fmaf(lo0.x, g0.x, A1xa); A1ya = fmaf(lo0.x, g0.y, A1ya); A1za = fmaf(lo0.x, g0.z, A1za);
        V0a += lo0.y; V1a += hi0.x; V2a += hi0.y;
        T3a = fmaf(lo0.y, g0.x, fmaf(hi0.x, g0.y, fmaf(hi0.y, g0.z, T3a)));
        A0b += lo1.x;
        A1xb = fmaf(lo1.x, g1.x, A1xb); A1yb = fmaf(lo1.x, g1.y, A1yb); A1zb = fmaf(lo1.x, g1.z, A1zb);
        V0b += lo1.y; V1b += hi1.x; V2b += hi1.y;
        T3b = fmaf(lo1.y, g1.x, fmaf(hi1.x, g1.y, fmaf(hi1.y, g1.z, T3b)));
    }

    // cross-half reduce (lanes L, L+32 hold same channel over disjoint edges)
    A0a += __shfl_xor(A0a, 32);  A1xa += __shfl_xor(A1xa, 32);
    A1ya += __shfl_xor(A1ya, 32); A1za += __shfl_xor(A1za, 32);
    V0a += __shfl_xor(V0a, 32);  V1a += __shfl_xor(V1a, 32);
    V2a += __shfl_xor(V2a, 32);  T3a += __shfl_xor(T3a, 32);
    A0b += __shfl_xor(A0b, 32);  A1xb += __shfl_xor(A1xb, 32);
    A1yb += __shfl_xor(A1yb, 32); A1zb += __shfl_xor(A1zb, 32);
    V0b += __shfl_xor(V0b, 32);  V1b += __shfl_xor(V1b, 32);
    V2b += __shfl_xor(V2b, 32);  T3b += __shfl_xor(T3b, 32);

    // SoA aggregates per node: [0,32)=s-path raw {A0|A1x/y/z}, [32,64)=v-path {T3|V0/1/2}
    int k = half ? (32 + cl) : cl;
    sS[w][0][k] = half ? T3a : A0a;
    sX[w][0][k] = half ? V0a : A1xa;
    sY[w][0][k] = half ? V1a : A1ya;
    sZ[w][0][k] = half ? V2a : A1za;
    sS[w][1][k] = half ? T3b : A0b;
    sX[w][1][k] = half ? V0b : A1xb;
    sY[w][1][k] = half ? V1b : A1yb;
    sZ[w][1][k] = half ? V2b : A1zb;
    WAVE_SYNC();

    // epilogue per node: outputs j = lane, lane+64; h2 weights, lane-coalesced
    #pragma unroll
    for (int ni = 0; ni < 2; ++ni) {
        if (ni == 1 && !has1) break;
        size_t ob = (size_t)(n0 + ni) * 128;
        #pragma unroll
        for (int t = 0; t < 2; ++t) {
            int j = lane + 64 * t;
            const float *ap;
            const __half2 *wp2;
            if (j < 32) {
                ap = sS[w][ni]; wp2 = WS2 + j;
            } else {
                int v = j - 32;
                int o = v / 3, mm = v - 3 * o;
                ap = (mm == 0) ? sX[w][ni] : (mm == 1) ? sY[w][ni] : sZ[w][ni];
                wp2 = WV2 + o;
            }
            float r = 0.f;
            #pragma unroll
            for (int q = 0; q < 16; ++q) {
                float4 a = *(const float4*)(ap + 4 * q);
                float2 w0 = __half22float2(wp2[(2 * q)     * 32]);
                float2 w1 = __half22float2(wp2[(2 * q + 1) * 32]);
                r = fmaf(a.x, w0.x, r); r = fmaf(a.y, w0.y, r);
                r = fmaf(a.z, w1.x, r); r = fmaf(a.w, w1.y, r);
            }
            out[ob + j] = r;               // all scales folded into WS2/WV2
        }
    }
}

extern "C" void kernel_launch(void* const* d_in, const int* in_sizes, int n_in,
                              void* d_out, int out_size, void* d_ws, size_t ws_size,
                              hipStream_t stream) {
    const float* feat = (const float*)d_in[0];
    const float* pos  = (const float*)d_in[1];
    const int*   esrc = (const int*)d_in[2];
    const int*   edst = (const int*)d_in[3];
    const float* tpw  = (const float*)d_in[4];
    const float* Ws   = (const float*)d_in[5];
    const float* Wv   = (const float*)d_in[6];
    float* out = (float*)d_out;

    int N = in_sizes[0] / 128;
    int E = in_sizes[2];

    uint2*   featH = (uint2*)d_ws;                            // (N+1)*32 uint2
    float4*  pos4  = (float4*)(featH + (size_t)(N + 1) * 32); // N
    int*     csrP  = (int*)(pos4 + N);                        // N*CAP
    int*     cnt   = csrP + (size_t)N * CAP;                  // N
    __half2* WS2   = (__half2*)(cnt + N);                     // 1024
    __half2* WV2   = WS2 + 1024;                              // 1024

    const int tb = 256;
    int prepTot = N * 32 + 32 + N + 1024;
    int ebk = (E / 4 + tb) / tb;
    prep_kernel<<<(prepTot + tb - 1) / tb, tb, 0, stream>>>(feat, pos, Ws, Wv, tpw,
                                                            featH, pos4, cnt, WS2, WV2, N);
    scatter_kernel<<<ebk, tb, 0, stream>>>(esrc, edst, cnt, csrP, E);
    node_kernel<<<(N + 7) / 8, 256, 0, stream>>>(featH, pos4, csrP, cnt, WS2, WV2, out, N);
}

// Round 17
// 108.043 us; speedup vs baseline: 1.0533x; 1.0533x over previous
//
#include <hip/hip_runtime.h>
#include <hip/hip_fp16.h>

#define SQRT3 1.7320508075688772f
#define INV_SQRT3 0.5773502691896258f
#define CAP 64

#define WAVE_SYNC() do { asm volatile("s_waitcnt lgkmcnt(0)" ::: "memory"); \
                         __builtin_amdgcn_wave_barrier(); } while (0)

// ---------------- fused prep: featH(f16) + pos4 + folded h2-packed weights + cnt=0 ----
// featH[node*32+cl] = half4{s_cl, v_cl0, v_cl1, v_cl2}  (256 B per node, contiguous)
// WS2[u2*32+j] = h2{fs(2u2,j), fs(2u2+1,j)};  WV2 likewise (all scales folded)
__global__ void prep_kernel(const float* __restrict__ feat, const float* __restrict__ pos,
                            const float* __restrict__ Ws, const float* __restrict__ Wv,
                            const float* __restrict__ tpw,
                            uint2* __restrict__ featH, float4* __restrict__ pos4,
                            int* __restrict__ cnt,
                            __half2* __restrict__ WS2, __half2* __restrict__ WV2, int N) {
    int i = blockIdx.x * blockDim.x + threadIdx.x;
    int totalF = N * 32;
    if (i < totalF) {
        int node = i >> 5, cl = i & 31;
        const float* fb = feat + (size_t)node * 128;
        float s  = fb[cl];
        float v0 = fb[32 + 3 * cl], v1 = fb[33 + 3 * cl], v2 = fb[34 + 3 * cl];
        __half2 h0 = __floats2half2_rn(s, v0);
        __half2 h1 = __floats2half2_rn(v1, v2);
        uint2 r;
        r.x = *(const unsigned int*)&h0;
        r.y = *(const unsigned int*)&h1;
        featH[i] = r;
        return;
    }
    int j = i - totalF;
    if (j < N) {
        pos4[j] = make_float4(pos[3 * j], pos[3 * j + 1], pos[3 * j + 2], 0.f);
        cnt[j] = 0;                        // zero scatter cursors (no memset pass)
        return;
    }
    int k = j - N;
    if (k < 1024) {                        // u2 = k>>5 in [0,32), col = k&31
        int u2 = k >> 5, c = k & 31;
        int ua = 2 * u2, ub = 2 * u2 + 1;
        auto fs = [&](int u) {
            float w = Ws[u * 32 + c];
            return (u < 32) ? 0.125f * tpw[u] * w
                            : 0.125f * tpw[96 + (u - 32)] * INV_SQRT3 * w;
        };
        auto fv = [&](int u) {
            float w = Wv[u * 32 + c];
            return (u < 32) ? 0.125f * tpw[32 + u] * w
                            : 0.125f * tpw[64 + (u - 32)] * w;
        };
        WS2[k] = __floats2half2_rn(fs(ua), fs(ub));
        WV2[k] = __floats2half2_rn(fv(ua), fv(ub));
    }
}

// ---------------- single-pass padded-CSR scatter: 1 edge/thread (max TLP) ----------
// p = atomicAdd(cursor); csrP[d*CAP+p] = s.  Afterwards cnt[d] == degree(d).
// 1 edge per thread -> 4x the waves of the 4-edge version; the independent
// atomic->store chains are hidden by thread-level parallelism.
__global__ void scatter_kernel(const int* __restrict__ esrc, const int* __restrict__ edst,
                               int* __restrict__ cnt, int* __restrict__ csrP, int E) {
    int e = blockIdx.x * blockDim.x + threadIdx.x;
    if (e < E) {
        int s = esrc[e];
        int d = edst[e];
        int p = atomicAdd(&cnt[d], 1);
        if (p < CAP) csrP[(size_t)d * CAP + p] = s;
    }
}

// ---------------- per-node gather + TP + linear (EXACT R15 structure) ----------------
// 1 wave/node, HALF-wave per edge, lane owns channel cl = {s,v0,v1,v2} (f16x4, 8B).
// Geometry phase in LDS (si packed in geom.w); unroll-4 runtime loop + odd tail;
// epilogue lane-coalesced with h2-packed weights (64 VMEM instead of 128).

__global__ __launch_bounds__(256) void node_kernel(
    const uint2* __restrict__ featH, const float4* __restrict__ pos4,
    const int* __restrict__ csrP, const int* __restrict__ cnt,
    const __half2* __restrict__ WS2, const __half2* __restrict__ WV2,
    float* __restrict__ out, int N)
{
    __shared__ float4 geom[4][64];
    __shared__ float  sS[4][68], sX[4][68], sY[4][68], sZ[4][68];
    int lane = threadIdx.x & 63;
    int w    = threadIdx.x >> 6;
    int node = blockIdx.x * 4 + w;
    if (node >= N) return;                 // whole-wave exit; no block barriers used

    int deg = cnt[node];                   // cursor after scatter == degree
    int len = deg < CAP ? deg : CAP;
    int half = lane >> 5;
    int cl   = lane & 31;

    float4 pd = pos4[node];                // wave-uniform

    if (lane < len) {
        int s = csrP[(size_t)node * CAP + lane];
        float4 ps = pos4[s];
        float ex = pd.x - ps.x, ey = pd.y - ps.y, ez = pd.z - ps.z;
        float rr = SQRT3 * rsqrtf(ex * ex + ey * ey + ez * ez + 1e-12f);
        geom[w][lane] = make_float4(rr * ex, rr * ey, rr * ez, __int_as_float(s));
    }
    WAVE_SYNC();

    float A0 = 0.f, A1x = 0.f, A1y = 0.f, A1z = 0.f;   // s-channel cl: a0, a1
    float V0 = 0.f, V1 = 0.f, V2 = 0.f, T3 = 0.f;      // v-channel cl: a2, a3(raw)

    int even = len & ~1;
    #pragma unroll 4
    for (int m = 0; m < even; m += 2) {
        float4 g = geom[w][m + half];
        int si = __float_as_int(g.w);
        uint2 fr = featH[(size_t)si * 32 + cl];
        float2 lo = __half22float2(*(const __half2*)&fr.x);   // {s, v0}
        float2 hi = __half22float2(*(const __half2*)&fr.y);   // {v1, v2}
        A0 += lo.x;
        A1x = fmaf(lo.x, g.x, A1x); A1y = fmaf(lo.x, g.y, A1y); A1z = fmaf(lo.x, g.z, A1z);
        V0 += lo.y; V1 += hi.x; V2 += hi.y;
        T3 = fmaf(lo.y, g.x, fmaf(hi.x, g.y, fmaf(hi.y, g.z, T3)));
    }
    if (len & 1) {                         // odd tail: half 0 only
        if (half == 0) {
            float4 g = geom[w][len - 1];
            int si = __float_as_int(g.w);
            uint2 fr = featH[(size_t)si * 32 + cl];
            float2 lo = __half22float2(*(const __half2*)&fr.x);
            float2 hi = __half22float2(*(const __half2*)&fr.y);
            A0 += lo.x;
            A1x = fmaf(lo.x, g.x, A1x); A1y = fmaf(lo.x, g.y, A1y); A1z = fmaf(lo.x, g.z, A1z);
            V0 += lo.y; V1 += hi.x; V2 += hi.y;
            T3 = fmaf(lo.y, g.x, fmaf(hi.x, g.y, fmaf(hi.y, g.z, T3)));
        }
    }

    // cross-half reduce (lanes L, L+32 hold same channel over disjoint edges)
    A0 += __shfl_xor(A0, 32);  A1x += __shfl_xor(A1x, 32);
    A1y += __shfl_xor(A1y, 32); A1z += __shfl_xor(A1z, 32);
    V0 += __shfl_xor(V0, 32);  V1 += __shfl_xor(V1, 32);
    V2 += __shfl_xor(V2, 32);  T3 += __shfl_xor(T3, 32);

    // SoA aggregate: [0,32)=s-path raw {A0 | A1x/y/z}, [32,64)=v-path raw {T3 | V0/1/2}
    int k = half ? (32 + cl) : cl;
    sS[w][k] = half ? T3 : A0;
    sX[w][k] = half ? V0 : A1x;
    sY[w][k] = half ? V1 : A1y;
    sZ[w][k] = half ? V2 : A1z;
    WAVE_SYNC();

    // epilogue: outputs j = lane, lane+64; h2-packed weights, lane-coalesced loads
    size_t ob = (size_t)node * 128;
    #pragma unroll
    for (int t = 0; t < 2; ++t) {
        int j = lane + 64 * t;
        const float *ap;
        const __half2 *wp2;
        if (j < 32) {
            ap = sS[w]; wp2 = WS2 + j;
        } else {
            int v = j - 32;
            int o = v / 3, mm = v - 3 * o;
            ap = (mm == 0) ? sX[w] : (mm == 1) ? sY[w] : sZ[w];
            wp2 = WV2 + o;
        }
        float r = 0.f;
        #pragma unroll
        for (int q = 0; q < 16; ++q) {
            float4 a = *(const float4*)(ap + 4 * q);
            float2 w0 = __half22float2(wp2[(2 * q)     * 32]);
            float2 w1 = __half22float2(wp2[(2 * q + 1) * 32]);
            r = fmaf(a.x, w0.x, r); r = fmaf(a.y, w0.y, r);
            r = fmaf(a.z, w1.x, r); r = fmaf(a.w, w1.y, r);
        }
        out[ob + j] = r;                   // all scales folded into WS2/WV2
    }
}

extern "C" void kernel_launch(void* const* d_in, const int* in_sizes, int n_in,
                              void* d_out, int out_size, void* d_ws, size_t ws_size,
                              hipStream_t stream) {
    const float* feat = (const float*)d_in[0];
    const float* pos  = (const float*)d_in[1];
    const int*   esrc = (const int*)d_in[2];
    const int*   edst = (const int*)d_in[3];
    const float* tpw  = (const float*)d_in[4];
    const float* Ws   = (const float*)d_in[5];
    const float* Wv   = (const float*)d_in[6];
    float* out = (float*)d_out;

    int N = in_sizes[0] / 128;
    int E = in_sizes[2];

    uint2*   featH = (uint2*)d_ws;                      // N*32   (12.8 MB, 256 B/node)
    float4*  pos4  = (float4*)(featH + (size_t)N * 32); // N      (0.8 MB)
    int*     csrP  = (int*)(pos4 + N);                  // N*CAP  (12.8 MB)
    int*     cnt   = csrP + (size_t)N * CAP;            // N      (0.2 MB)
    __half2* WS2   = (__half2*)(cnt + N);               // 1024   (4 KB)
    __half2* WV2   = WS2 + 1024;                        // 1024   (4 KB)

    const int tb = 256;
    int prepTot = N * 32 + N + 1024;
    prep_kernel<<<(prepTot + tb - 1) / tb, tb, 0, stream>>>(feat, pos, Ws, Wv, tpw,
                                                            featH, pos4, cnt, WS2, WV2, N);
    scatter_kernel<<<(E + tb - 1) / tb, tb, 0, stream>>>(esrc, edst, cnt, csrP, E);
    node_kernel<<<(N + 3) / 4, 256, 0, stream>>>(featH, pos4, csrP, cnt, WS2, WV2, out, N);
}